// Round 5
// baseline (481.194 us; speedup 1.0000x reference)
//
#include <hip/hip_runtime.h>
#include <stdint.h>

#define N_IMG 32
#define C_IN 256
#define K_OUT 256
#define HW 56
#define HP 58
#define SPATIAL (N_IMG*HW*HW)          /* 100352 */
#define KDIM (C_IN*9)                  /* 2304 */
#define XPAD_ELEMS (N_IMG*HP*HP*C_IN)  /* 27557888 */
#define XPAD_BYTES (XPAD_ELEMS*2)      /* 55115776 */
#define WT_BYTES (K_OUT*KDIM*2)        /* 1179648 */
#define OUT_ELEMS (N_IMG*K_OUT*HW*HW)  /* 25690112 */

/* GEMM: BM=256 out-ch x BN=256 spatial, tap-structured K, 512 thr, grid 392.
   A (Wt) read direct global->VGPR (L1-resident, 1-tap register prefetch);
   B (xpad) LDS super-tile per 32-ch chunk, double-buffered. */
#define GRID_GEMM 392
#define BBUF 40960                 /* B super: 10 rowslots x 64 cols x 32ch x 2B */
#define LDS_TOT (2*BBUF)           /* 81920 */

/* prep grid partition */
#define PREP_X_BLOCKS (SPATIAL/64)          /* 1568 */
#define PREP_Z_BLOCKS ((N_IMG*228*32)/256)  /* 912 */
#define PREP_W_BLOCKS K_OUT                 /* 256 */
#define PREP_BLOCKS (PREP_X_BLOCKS+PREP_Z_BLOCKS+PREP_W_BLOCKS)

typedef __bf16 bf16x8 __attribute__((ext_vector_type(8)));
typedef float  f32x4  __attribute__((ext_vector_type(4)));

static __device__ __forceinline__ unsigned short f2bf(float f) {
    unsigned u = __float_as_uint(f);
    u += 0x7fff + ((u >> 16) & 1);   // RNE
    return (unsigned short)(u >> 16);
}

static __device__ __forceinline__ void gld16(const void* g, void* l) {
    __builtin_amdgcn_global_load_lds(
        (const __attribute__((address_space(1))) void*)g,
        (__attribute__((address_space(3))) void*)l, 16, 0, 0);
}

// ---------------- fused prep: x->NHWC bf16 padded, border zero, W transform ----
__global__ __launch_bounds__(256) void prep(
    const float* __restrict__ x, const float* __restrict__ W,
    unsigned short* __restrict__ xpad, unsigned short* __restrict__ Wt) {
    const int b = blockIdx.x, t = threadIdx.x;
    if (b < PREP_X_BLOCKS) {
        __shared__ __align__(16) unsigned short lds[64 * 256];   // 32 KB
        const int n = b / 49, hw0 = (b % 49) * 64;
        const int l = t & 63, w0 = t >> 6;
        const float* xbase = x + (size_t)(n * C_IN) * 3136 + hw0 + l;
        #pragma unroll
        for (int i = 0; i < 16; ++i) {
            const int c4 = w0 * 64 + i * 4;      // 4 consecutive channels
            unsigned short v[4];
            #pragma unroll
            for (int j = 0; j < 4; ++j)
                v[j] = f2bf(xbase[(c4 + j) * 3136]);
            const int m = c4 >> 3, h8 = (c4 >> 2) & 1;   // wave-uniform
            *(uint2*)&lds[l * 256 + ((m ^ (l & 31)) << 3) + h8 * 4] = *(const uint2*)v;
        }
        __syncthreads();
        const int q = t & 31;
        #pragma unroll
        for (int j = 0; j < 8; ++j) {
            const int p = (t >> 5) + j * 8;
            const int hw = hw0 + p, h = hw / 56, w = hw - h * 56;
            uint4 v = *(const uint4*)&lds[p * 256 + ((q ^ (p & 31)) << 3)];
            *(uint4*)&xpad[((n * HP + h + 1) * HP + (w + 1)) * C_IN + q * 8] = v;
        }
    } else if (b < PREP_X_BLOCKS + PREP_Z_BLOCKS) {
        // ---- zero the pad border (one uint4 per thread) ----
        int idx = (b - PREP_X_BLOCKS) * 256 + t;
        int cell = idx >> 5, qq = idx & 31;
        int n = cell / 228, r = cell - n * 228;
        int h, w;
        if (r < 58)       { h = 0;            w = r; }
        else if (r < 116) { h = 57;           w = r - 58; }
        else if (r < 172) { h = r - 116 + 1;  w = 0; }
        else              { h = r - 172 + 1;  w = 57; }
        uint4 z = make_uint4(0u, 0u, 0u, 0u);
        *(uint4*)&xpad[((n * HP + h) * HP + w) * C_IN + qq * 8] = z;
    } else {
        // ---- W fp32 OIHW -> bf16 [k][rs][c] ----
        const int k = b - PREP_X_BLOCKS - PREP_Z_BLOCKS, c = t;
        const float* wp = W + (k * C_IN + c) * 9;
        #pragma unroll
        for (int rs = 0; rs < 9; ++rs)
            Wt[k * KDIM + rs * C_IN + c] = f2bf(wp[rs]);
    }
}

// ---------------- main: implicit GEMM, A-from-global + B tap-reuse super-tile -
// K = chunk c (8 x 32ch) outer, tap t = (r,s) inner (9). Per chunk: B super =
// all xpad rows the block touches (true worst case 10 slots: non-crossing <=8,
// crossing tails are {64,128,192} pts -> exactly 10), 64 cols x 32ch, staged
// once, reused by 9 taps. A (Wt, 1.1 MB, L2/L1-resident; per-tap slice 16 KB
// shared by all waves -> L1 hits) is read straight to VGPRs with a 1-TAP
// REGISTER PREFETCH: at tap t load aF[next] for tap t+1; the compiler's own
// s_waitcnt for those regs orders everything. Consequences: no A LDS, no A
// ledger, and NO mid-chunk barriers -- 8 barriers/tile instead of 72. Chunk
// boundary: vmcnt(8) (a-frag prefetch of next tap may stay in flight; older
// B gld16s drain in-order) + s_barrier certifies B(c+1) and fences the par
// being overwritten. acc 128 + aF 64 regs: launch_bounds(512,2) pins the
// 256-reg tier (2 waves/SIMD). LDS chunk swizzle on B both sides (rule 21):
// phys16B = log16B ^ ((col>>1)&3) -> 2-way bank aliasing (free, m136).
__global__ __launch_bounds__(512, 2) void conv_gemm(
    const unsigned short* __restrict__ xpad,
    const unsigned short* __restrict__ Wt,
    float* __restrict__ out) {
    extern __shared__ __align__(16) char smem[];   // 81920 bytes dynamic
    const int tau = threadIdx.x;
    const int w0 = tau >> 6, l = tau & 63;
    const int wm = w0 >> 2, wn = w0 & 3;
    const int lm = l & 15, lq = l >> 4;
    const int bx = blockIdx.x;
    const int p0 = ((bx & 7) * 49 + (bx >> 3)) * 256;   // XCD-swizzled tile base

    // ---- block row-list: rows of n0 (+ seg of n1 if crossing) ----
    const int n0 = p0 / 3136, rem0 = p0 - n0 * 3136, h0 = rem0 / 56;
    const int pend = p0 + 255;
    const int n1 = pend / 3136, remE = pend - n1 * 3136, hE = remE / 56;
    const int L1 = (n1 != n0) ? (58 - h0) : (hE - h0 + 3);

    // ---- B staging: 5 issues x (2 slots); thread -> slot 2i+myHalf, col t8>>2,
    // phys 16B-chunk t8&3 (fetches swizzled logical chunk) ----
    const int myHalf = tau >> 8, t8 = tau & 255;
    const int colS = t8 >> 2;
    const int logS = (t8 & 3) ^ ((colS >> 1) & 3);
    const int srcColByte = colS * 512 + logS * 16;
    int rowBaseByte[5];
    #pragma unroll
    for (int i = 0; i < 5; ++i) {
        int slot = i * 2 + myHalf;
        int xr = (slot < L1) ? (n0 * 58 + h0 + slot) : (n1 * 58 + (slot - L1));
        rowBaseByte[i] = xr * 29696;          // xpad row = 58 cols x 256 ch x 2B
    }

    // ---- A direct-global addressing: row=wm*128+i2*16+lm, k-chunk lq ----
    const int laneA = (wm * 128 + lm) * 4608 + lq * 16;   // bytes into Wt

    // ---- B fragment precompute ----
    int bB[4], wv[4];
    #pragma unroll
    for (int tj = 0; tj < 4; ++tj) {
        int p = p0 + wn * 64 + tj * 16 + lm;
        int n = p / 3136, remp = p - n * 3136;
        int h = remp / 56, w = remp - h * 56;
        int rowIdx0 = (n == n0) ? (h - h0) : (L1 + h);
        bB[tj] = rowIdx0 * 4096 + w * 64;
        wv[tj] = w;
    }

    f32x4 acc[8][4] = {};
    bf16x8 aF[2][8];

#define SB(par, i, cn) \
    gld16((const char*)xpad + rowBaseByte[i] + (cn) * 64 + srcColByte, \
          smem + (par) * BBUF + ((i) * 2 + myHalf) * 4096 + t8 * 16)
#define BAR() asm volatile("s_barrier" ::: "memory")

    // ---- prologue: B(chunk0)->par0; prefetch aF[0] = frags(c0,t0) ----
    #pragma unroll
    for (int i = 0; i < 5; ++i) SB(0, i, 0);
    {
        const char* ap = (const char*)Wt + laneA;        // kByte = 0
        #pragma unroll
        for (int i2 = 0; i2 < 8; ++i2)
            aF[0][i2] = *(const bf16x8*)(ap + i2 * 73728);
    }
    asm volatile("s_waitcnt vmcnt(8)" ::: "memory");     // B(c0) resident
    BAR();

#define TAP_BODY(CPAR, T) do { \
    if ((T) < 5) SB(((c + 1) & 1), (T), cnext); \
    { /* prefetch A frags for tap T+1 (wraps into next chunk at T==8) */ \
      const int kN = ((T) < 8) ? (((T) + 1) * 512 + c * 64) : ((c + 1) * 64); \
      const char* ap = (const char*)Wt + laneA + kN; \
      _Pragma("unroll") \
      for (int i2 = 0; i2 < 8; ++i2) \
          aF[((CPAR) + (T) + 1) & 1][i2] = *(const bf16x8*)(ap + i2 * 73728); } \
    { const int r = (T) / 3, s = (T) - r * 3; \
      bf16x8 b[4]; \
      _Pragma("unroll") \
      for (int tj = 0; tj < 4; ++tj) \
          b[tj] = *(const bf16x8*)(Bc + bB[tj] + r * 4096 + s * 64 \
                    + ((lq ^ (((wv[tj] + s) >> 1) & 3)) << 4)); \
      __builtin_amdgcn_s_setprio(1); \
      _Pragma("unroll") \
      for (int i2 = 0; i2 < 8; ++i2) \
          _Pragma("unroll") \
          for (int tj = 0; tj < 4; ++tj) \
              acc[i2][tj] = __builtin_amdgcn_mfma_f32_16x16x32_bf16( \
                  aF[((CPAR) + (T)) & 1][i2], b[tj], acc[i2][tj], 0, 0, 0); \
      __builtin_amdgcn_s_setprio(0); } \
    if ((T) == 8) { \
        asm volatile("s_waitcnt vmcnt(8)" ::: "memory"); \
        BAR(); \
    } \
} while (0)

    for (int cc = 0; cc < 4; ++cc) {
        {   // even chunk (parity 0), B in par0
            const int c = 2 * cc;
            const int cnext = c + 1;
            const char* Bc = smem;
            #pragma unroll
            for (int T = 0; T < 9; ++T) TAP_BODY(0, T);
        }
        {   // odd chunk (parity 1), B in par1
            const int c = 2 * cc + 1;
            const int cnext = (c + 1) & 7;               // wraps harmlessly at c=7
            const char* Bc = smem + BBUF;
            #pragma unroll
            for (int T = 0; T < 9; ++T) TAP_BODY(1, T);
        }
    }
    asm volatile("s_waitcnt vmcnt(0)" ::: "memory");     // drain stray gld16

    // ---- epilogue: C/D layout col=lane&15 (spatial), row=lq*4+r2 (out-ch) ----
    int obase[4];
    #pragma unroll
    for (int tj = 0; tj < 4; ++tj) {
        int p = p0 + wn * 64 + tj * 16 + lm;
        int n = p / 3136; int rem = p - n * 3136;
        obase[tj] = n * (K_OUT * 3136) + rem;
    }
    const int kb = wm * 128 + lq * 4;
    #pragma unroll
    for (int ti = 0; ti < 8; ++ti)
        #pragma unroll
        for (int tj = 0; tj < 4; ++tj) {
            float* op = out + obase[tj] + (kb + ti * 16) * 3136;
            #pragma unroll
            for (int r2 = 0; r2 < 4; ++r2)
                op[r2 * 3136] = acc[ti][tj][r2];
        }
#undef SB
#undef BAR
#undef TAP_BODY
}

// ---------------- fallback (only if ws too small): naive fp32 direct conv ----------------
__global__ void conv_naive(const float* __restrict__ x, const float* __restrict__ W,
                           float* __restrict__ out, int total) {
    int idx = blockIdx.x * 256 + threadIdx.x;
    if (idx >= total) return;
    int n = idx / (K_OUT * 3136); int rem = idx - n * (K_OUT * 3136);
    int k = rem / 3136; rem -= k * 3136;
    int h = rem / 56; int w = rem - h * 56;
    float acc = 0.f;
    for (int c = 0; c < C_IN; ++c) {
        const float* xp = x + ((n * C_IN + c) * HW) * HW;
        const float* wp = W + (k * C_IN + c) * 9;
        #pragma unroll
        for (int r = 0; r < 3; ++r) {
            int hh = h + r - 1;
            if ((unsigned)hh >= HW) continue;
            #pragma unroll
            for (int s = 0; s < 3; ++s) {
                int ww = w + s - 1;
                if ((unsigned)ww >= HW) continue;
                acc += xp[hh * HW + ww] * wp[r * 3 + s];
            }
        }
    }
    out[idx] = acc;
}

extern "C" void kernel_launch(void* const* d_in, const int* in_sizes, int n_in,
                              void* d_out, int out_size, void* d_ws, size_t ws_size,
                              hipStream_t stream) {
    const float* x = (const float*)d_in[0];
    const float* W = (const float*)d_in[1];
    float* out = (float*)d_out;
    const size_t need = (size_t)XPAD_BYTES + WT_BYTES;
    if (ws_size >= need) {
        static bool attr_done = false;
        if (!attr_done) {
            hipFuncSetAttribute((const void*)conv_gemm,
                                hipFuncAttributeMaxDynamicSharedMemorySize, LDS_TOT);
            attr_done = true;
        }
        unsigned short* xpad = (unsigned short*)d_ws;
        unsigned short* Wt = (unsigned short*)((char*)d_ws + XPAD_BYTES);
        prep<<<PREP_BLOCKS, 256, 0, stream>>>(x, W, xpad, Wt);
        conv_gemm<<<GRID_GEMM, 512, LDS_TOT, stream>>>(xpad, Wt, out);
    } else {
        conv_naive<<<(OUT_ELEMS + 255) / 256, 256, 0, stream>>>(x, W, out, OUT_ELEMS);
    }
}

// Round 6
// 326.164 us; speedup vs baseline: 1.4753x; 1.4753x over previous
//
#include <hip/hip_runtime.h>
#include <stdint.h>

#define N_IMG 32
#define C_IN 256
#define K_OUT 256
#define HW 56
#define HP 58
#define SPATIAL (N_IMG*HW*HW)          /* 100352 */
#define KDIM (C_IN*9)                  /* 2304 */
#define XPAD_ELEMS (N_IMG*HP*HP*C_IN)  /* 27557888 */
#define XPAD_BYTES (XPAD_ELEMS*2)      /* 55115776 */
#define WT_BYTES (K_OUT*KDIM*2)        /* 1179648 */
#define OUT_ELEMS (N_IMG*K_OUT*HW*HW)  /* 25690112 */

/* GEMM: BM=256 out-ch x BN=112 spatial (= 2 whole rows; 3136 = 28*112 so no
   tile ever crosses an image), 256 thr = 4 waves, grid 896 = 8 XCD x 112.
   A (Wt) direct global->VGPR, 1-tap register prefetch. B (xpad) LDS super
   tile: 4 row-slots x 64 cols x 32 ch, double-buffered = 32 KB total LDS.
   Budget: acc 112 (AGPR) + aF 32 + misc ~70 => ~215 of the 256/lane cap at
   2 waves/SIMD -> 2 blocks/CU (this is what round 5 got wrong). */
#define GRID_GEMM 896
#define BBUF 16384
#define LDS_TOT (2*BBUF)               /* 32768 */

/* prep grid partition */
#define PREP_X_BLOCKS (SPATIAL/64)          /* 1568 */
#define PREP_Z_BLOCKS ((N_IMG*228*32)/256)  /* 912 */
#define PREP_W_BLOCKS K_OUT                 /* 256 */
#define PREP_BLOCKS (PREP_X_BLOCKS+PREP_Z_BLOCKS+PREP_W_BLOCKS)

typedef __bf16 bf16x8 __attribute__((ext_vector_type(8)));
typedef float  f32x4  __attribute__((ext_vector_type(4)));

static __device__ __forceinline__ unsigned short f2bf(float f) {
    unsigned u = __float_as_uint(f);
    u += 0x7fff + ((u >> 16) & 1);   // RNE
    return (unsigned short)(u >> 16);
}

static __device__ __forceinline__ void gld16(const void* g, void* l) {
    __builtin_amdgcn_global_load_lds(
        (const __attribute__((address_space(1))) void*)g,
        (__attribute__((address_space(3))) void*)l, 16, 0, 0);
}

// ---------------- fused prep: x->NHWC bf16 padded, border zero, W transform ----
__global__ __launch_bounds__(256) void prep(
    const float* __restrict__ x, const float* __restrict__ W,
    unsigned short* __restrict__ xpad, unsigned short* __restrict__ Wt) {
    const int b = blockIdx.x, t = threadIdx.x;
    if (b < PREP_X_BLOCKS) {
        __shared__ __align__(16) unsigned short lds[64 * 256];   // 32 KB
        const int n = b / 49, hw0 = (b % 49) * 64;
        const int l = t & 63, w0 = t >> 6;
        const float* xbase = x + (size_t)(n * C_IN) * 3136 + hw0 + l;
        #pragma unroll
        for (int i = 0; i < 16; ++i) {
            const int c4 = w0 * 64 + i * 4;      // 4 consecutive channels
            unsigned short v[4];
            #pragma unroll
            for (int j = 0; j < 4; ++j)
                v[j] = f2bf(xbase[(c4 + j) * 3136]);
            const int m = c4 >> 3, h8 = (c4 >> 2) & 1;   // wave-uniform
            *(uint2*)&lds[l * 256 + ((m ^ (l & 31)) << 3) + h8 * 4] = *(const uint2*)v;
        }
        __syncthreads();
        const int q = t & 31;
        #pragma unroll
        for (int j = 0; j < 8; ++j) {
            const int p = (t >> 5) + j * 8;
            const int hw = hw0 + p, h = hw / 56, w = hw - h * 56;
            uint4 v = *(const uint4*)&lds[p * 256 + ((q ^ (p & 31)) << 3)];
            *(uint4*)&xpad[((n * HP + h + 1) * HP + (w + 1)) * C_IN + q * 8] = v;
        }
    } else if (b < PREP_X_BLOCKS + PREP_Z_BLOCKS) {
        // ---- zero the pad border (one uint4 per thread) ----
        int idx = (b - PREP_X_BLOCKS) * 256 + t;
        int cell = idx >> 5, qq = idx & 31;
        int n = cell / 228, r = cell - n * 228;
        int h, w;
        if (r < 58)       { h = 0;            w = r; }
        else if (r < 116) { h = 57;           w = r - 58; }
        else if (r < 172) { h = r - 116 + 1;  w = 0; }
        else              { h = r - 172 + 1;  w = 57; }
        uint4 z = make_uint4(0u, 0u, 0u, 0u);
        *(uint4*)&xpad[((n * HP + h) * HP + w) * C_IN + qq * 8] = z;
    } else {
        // ---- W fp32 OIHW -> bf16 [k][rs][c] ----
        const int k = b - PREP_X_BLOCKS - PREP_Z_BLOCKS, c = t;
        const float* wp = W + (k * C_IN + c) * 9;
        #pragma unroll
        for (int rs = 0; rs < 9; ++rs)
            Wt[k * KDIM + rs * C_IN + c] = f2bf(wp[rs]);
    }
}

// ---------------- main: implicit GEMM, A-direct + 2-row B super-tile ----------
// K = chunk c (8 x 32ch) outer, tap T=(r,s) inner. B super: padded xpad rows
// h0..h0+3 (out rows h0,h0+1 need exactly these; never crosses an image since
// 112 | 3136), 64 cols x 32ch, staged once per chunk, reused by 9 taps.
// A: each wave owns 64 out-ch; per tap 4 x global dwordx4 per lane straight to
// VGPR (Wt 1.15 MB is L2-resident on every XCD), double-buffered aF[2][4] with
// a 1-tap prefetch; the compiler's own vmcnt before MFMA (leaves the 4 newest
// in flight) is the ordering. NO per-tap barriers: the only LDS hazard is the
// B parity buffer, certified once per chunk by vmcnt(4)-before-barrier (B
// shares are issued taps 0-3, 5+ taps older than the wait; the 4 newest = aF
// prefetch ride across the barrier -- counted, never drained mid-loop).
// LDS swizzle both sides (rule 21): phys16 = log16 ^ (col&3) -> ~2-way bank
// aliasing (free per m136) on ds_read_b128. Staging dst is linear tau*16
// (gld16 wave-uniform-base requirement); source pre-swizzled.
__global__ __launch_bounds__(256, 2) void conv_gemm(
    const unsigned short* __restrict__ xpad,
    const unsigned short* __restrict__ Wt,
    float* __restrict__ out) {
    extern __shared__ __align__(16) char smem[];   // 32768 bytes dynamic
    const int tau = threadIdx.x;
    const int w0 = tau >> 6, l = tau & 63;
    const int lm = l & 15, lq = l >> 4;
    const int bx = blockIdx.x;
    const int tile = (bx & 7) * 112 + (bx >> 3);    // bijective XCD swizzle
    const int p0 = tile * 112;
    const int n0 = tile / 28;                       // 28 tiles per image
    const int rem0 = p0 - n0 * 3136;
    const int h0 = rem0 / 56;                       // even, 0..54

    // ---- B staging: issue i = row-slot i; thread -> col tau>>2, phys chunk
    // tau&3, fetches logical chunk (tau&3)^(col&3) ----
    const int colS = tau >> 2;
    const int logS = (tau & 3) ^ (colS & 3);
    const int srcB0 = (n0 * 58 + h0) * 29696 + colS * 512 + logS * 16;
    const int dstB = tau * 16;                      // + par*BBUF + slot*4096

    // ---- A direct-global: lane row = w0*64 + ti*16 + lm, k-sub lq ----
    const int laneA = (w0 * 64 + lm) * 4608 + lq * 16;   // + ti*73728 + T*512 + c*64

    // ---- B fragment precompute: pt = tj*16+lm -> row ri, col wv ----
    int bSlot[7], wv[7];
    #pragma unroll
    for (int tj = 0; tj < 7; ++tj) {
        int pt = tj * 16 + lm;
        int ri = (pt >= 56) ? 1 : 0;
        bSlot[tj] = ri * 4096;
        wv[tj] = pt - ri * 56;
    }

    f32x4 acc[4][7] = {};
    bf16x8 aF[2][4];     // all indices compile-time after full unroll (rule 20)

#define BAR() asm volatile("s_barrier" ::: "memory")
#define TAP(C, T) do { \
    if ((T) < 4 && (C) < 7) \
        gld16((const char*)xpad + srcB0 + (T) * 29696 + ((C) + 1) * 64, \
              smem + (((C) + 1) & 1) * BBUF + (T) * 4096 + dstB); \
    { const int kN = ((T) < 8) ? (((T) + 1) * 512 + (C) * 64) \
                               : ((((C) + 1) & 7) * 64); \
      const char* ap = (const char*)Wt + laneA + kN; \
      _Pragma("unroll") \
      for (int ti = 0; ti < 4; ++ti) \
          aF[((C) * 9 + (T) + 1) & 1][ti] = *(const bf16x8*)(ap + ti * 73728); } \
    { const int r = (T) / 3, s = (T) - ((T) / 3) * 3; \
      const char* Bc = smem + ((C) & 1) * BBUF + r * 4096 + s * 64; \
      bf16x8 b[7]; \
      _Pragma("unroll") \
      for (int tj = 0; tj < 7; ++tj) { \
          const int cs = wv[tj] + s; \
          b[tj] = *(const bf16x8*)(Bc + bSlot[tj] + wv[tj] * 64 \
                    + ((lq ^ (cs & 3)) * 16)); } \
      __builtin_amdgcn_s_setprio(1); \
      _Pragma("unroll") \
      for (int ti = 0; ti < 4; ++ti) \
          _Pragma("unroll") \
          for (int tj = 0; tj < 7; ++tj) \
              acc[ti][tj] = __builtin_amdgcn_mfma_f32_16x16x32_bf16( \
                  aF[((C) * 9 + (T)) & 1][ti], b[tj], acc[ti][tj], 0, 0, 0); \
      __builtin_amdgcn_s_setprio(0); } \
    if ((T) == 8) { \
        if ((C) < 7) asm volatile("s_waitcnt vmcnt(4)" ::: "memory"); \
        else         asm volatile("s_waitcnt vmcnt(0)" ::: "memory"); \
        BAR(); \
    } \
} while (0)

    // ---- prologue: B(chunk0)->par0 (4 issues), aF[0] = frags(c0,tap0) ----
    #pragma unroll
    for (int i = 0; i < 4; ++i)
        gld16((const char*)xpad + srcB0 + i * 29696, smem + i * 4096 + dstB);
    {
        const char* ap = (const char*)Wt + laneA;
        #pragma unroll
        for (int ti = 0; ti < 4; ++ti)
            aF[0][ti] = *(const bf16x8*)(ap + ti * 73728);
    }
    asm volatile("s_waitcnt vmcnt(4)" ::: "memory");   // B(c0) resident; aF rides
    BAR();

    #pragma unroll
    for (int cc = 0; cc < 4; ++cc) {
        #pragma unroll
        for (int T = 0; T < 9; ++T) TAP(2 * cc, T);
        #pragma unroll
        for (int T = 0; T < 9; ++T) TAP(2 * cc + 1, T);
    }
    asm volatile("s_waitcnt vmcnt(0)" ::: "memory");   // drain wrap prefetch

    // ---- epilogue: C/D layout col=lane&15 (spatial), row=lq*4+r2 (out-ch) ----
    const int obase0 = n0 * (K_OUT * 3136) + rem0 + lm;
    const int kb = w0 * 64 + lq * 4;
    #pragma unroll
    for (int ti = 0; ti < 4; ++ti)
        #pragma unroll
        for (int tj = 0; tj < 7; ++tj) {
            float* op = out + obase0 + tj * 16 + (kb + ti * 16) * 3136;
            #pragma unroll
            for (int r2 = 0; r2 < 4; ++r2)
                op[r2 * 3136] = acc[ti][tj][r2];
        }
#undef TAP
#undef BAR
}

// ---------------- fallback (only if ws too small): naive fp32 direct conv ----------------
__global__ void conv_naive(const float* __restrict__ x, const float* __restrict__ W,
                           float* __restrict__ out, int total) {
    int idx = blockIdx.x * 256 + threadIdx.x;
    if (idx >= total) return;
    int n = idx / (K_OUT * 3136); int rem = idx - n * (K_OUT * 3136);
    int k = rem / 3136; rem -= k * 3136;
    int h = rem / 56; int w = rem - h * 56;
    float acc = 0.f;
    for (int c = 0; c < C_IN; ++c) {
        const float* xp = x + ((n * C_IN + c) * HW) * HW;
        const float* wp = W + (k * C_IN + c) * 9;
        #pragma unroll
        for (int r = 0; r < 3; ++r) {
            int hh = h + r - 1;
            if ((unsigned)hh >= HW) continue;
            #pragma unroll
            for (int s = 0; s < 3; ++s) {
                int ww = w + s - 1;
                if ((unsigned)ww >= HW) continue;
                acc += xp[hh * HW + ww] * wp[r * 3 + s];
            }
        }
    }
    out[idx] = acc;
}

extern "C" void kernel_launch(void* const* d_in, const int* in_sizes, int n_in,
                              void* d_out, int out_size, void* d_ws, size_t ws_size,
                              hipStream_t stream) {
    const float* x = (const float*)d_in[0];
    const float* W = (const float*)d_in[1];
    float* out = (float*)d_out;
    const size_t need = (size_t)XPAD_BYTES + WT_BYTES;
    if (ws_size >= need) {
        unsigned short* xpad = (unsigned short*)d_ws;
        unsigned short* Wt = (unsigned short*)((char*)d_ws + XPAD_BYTES);
        prep<<<PREP_BLOCKS, 256, 0, stream>>>(x, W, xpad, Wt);
        conv_gemm<<<GRID_GEMM, 256, LDS_TOT, stream>>>(xpad, Wt, out);
    } else {
        conv_naive<<<(OUT_ELEMS + 255) / 256, 256, 0, stream>>>(x, W, out, OUT_ELEMS);
    }
}

// Round 7
// 324.560 us; speedup vs baseline: 1.4826x; 1.0049x over previous
//
#include <hip/hip_runtime.h>
#include <stdint.h>

#define N_IMG 32
#define C_IN 256
#define K_OUT 256
#define HW 56
#define HP 58
#define SPATIAL (N_IMG*HW*HW)          /* 100352 */
#define KDIM (C_IN*9)                  /* 2304 */
#define XPAD_ELEMS (N_IMG*HP*HP*C_IN)  /* 27557888 */
#define XPAD_BYTES (XPAD_ELEMS*2)      /* 55115776 */
#define WT_BYTES (K_OUT*KDIM*2)        /* 1179648 */
#define OUT_ELEMS (N_IMG*K_OUT*HW*HW)  /* 25690112 */

/* GEMM: BM=256 out-ch x BN=112 spatial (2 whole rows; 112 | 3136 so tiles
   never cross an image), 256 thr = 4 waves, grid 896 = 8 XCD x 112.
   A (Wt) direct global->VGPR, 3-buffer distance-2 register prefetch.
   B (xpad) LDS super-tile 4 slots x 64 cols x 32 ch, double-buffered (32 KB). */
#define GRID_GEMM 896
#define BBUF 16384
#define LDS_TOT (2*BBUF)               /* 32768 */

/* prep grid partition */
#define PREP_X_BLOCKS (SPATIAL/64)          /* 1568 */
#define PREP_Z_BLOCKS ((N_IMG*228*32)/256)  /* 912 */
#define PREP_W_BLOCKS K_OUT                 /* 256 */
#define PREP_BLOCKS (PREP_X_BLOCKS+PREP_Z_BLOCKS+PREP_W_BLOCKS)

typedef __bf16 bf16x8 __attribute__((ext_vector_type(8)));
typedef float  f32x4  __attribute__((ext_vector_type(4)));

static __device__ __forceinline__ unsigned short f2bf(float f) {
    unsigned u = __float_as_uint(f);
    u += 0x7fff + ((u >> 16) & 1);   // RNE
    return (unsigned short)(u >> 16);
}

static __device__ __forceinline__ void gld16(const void* g, void* l) {
    __builtin_amdgcn_global_load_lds(
        (const __attribute__((address_space(1))) void*)g,
        (__attribute__((address_space(3))) void*)l, 16, 0, 0);
}

// ---------------- fused prep: x->NHWC bf16 padded, border zero, W transform ----
__global__ __launch_bounds__(256) void prep(
    const float* __restrict__ x, const float* __restrict__ W,
    unsigned short* __restrict__ xpad, unsigned short* __restrict__ Wt) {
    const int b = blockIdx.x, t = threadIdx.x;
    if (b < PREP_X_BLOCKS) {
        __shared__ __align__(16) unsigned short lds[64 * 256];   // 32 KB
        const int n = b / 49, hw0 = (b % 49) * 64;
        const int l = t & 63, w0 = t >> 6;
        const float* xbase = x + (size_t)(n * C_IN) * 3136 + hw0 + l;
        #pragma unroll
        for (int i = 0; i < 16; ++i) {
            const int c4 = w0 * 64 + i * 4;      // 4 consecutive channels
            unsigned short v[4];
            #pragma unroll
            for (int j = 0; j < 4; ++j)
                v[j] = f2bf(xbase[(c4 + j) * 3136]);
            const int m = c4 >> 3, h8 = (c4 >> 2) & 1;   // wave-uniform
            *(uint2*)&lds[l * 256 + ((m ^ (l & 31)) << 3) + h8 * 4] = *(const uint2*)v;
        }
        __syncthreads();
        const int q = t & 31;
        #pragma unroll
        for (int j = 0; j < 8; ++j) {
            const int p = (t >> 5) + j * 8;
            const int hw = hw0 + p, h = hw / 56, w = hw - h * 56;
            uint4 v = *(const uint4*)&lds[p * 256 + ((q ^ (p & 31)) << 3)];
            *(uint4*)&xpad[((n * HP + h + 1) * HP + (w + 1)) * C_IN + q * 8] = v;
        }
    } else if (b < PREP_X_BLOCKS + PREP_Z_BLOCKS) {
        // ---- zero the pad border (one uint4 per thread) ----
        int idx = (b - PREP_X_BLOCKS) * 256 + t;
        int cell = idx >> 5, qq = idx & 31;
        int n = cell / 228, r = cell - n * 228;
        int h, w;
        if (r < 58)       { h = 0;            w = r; }
        else if (r < 116) { h = 57;           w = r - 58; }
        else if (r < 172) { h = r - 116 + 1;  w = 0; }
        else              { h = r - 172 + 1;  w = 57; }
        uint4 z = make_uint4(0u, 0u, 0u, 0u);
        *(uint4*)&xpad[((n * HP + h) * HP + w) * C_IN + qq * 8] = z;
    } else {
        // ---- W fp32 OIHW -> bf16 [k][rs][c] ----
        const int k = b - PREP_X_BLOCKS - PREP_Z_BLOCKS, c = t;
        const float* wp = W + (k * C_IN + c) * 9;
        #pragma unroll
        for (int rs = 0; rs < 9; ++rs)
            Wt[k * KDIM + rs * C_IN + c] = f2bf(wp[rs]);
    }
}

// ---------------- main: implicit GEMM, A-direct(3-deep) + 2-row B super-tile --
// K = chunk c (8 x 32ch) outer, tap T=(r,s) inner. B super: padded rows
// h0..h0+3, 64 cols x 32ch, staged once per chunk (taps 0-3), reused 9 taps.
// A: per tap 4 x dwordx4/lane straight to VGPR (Wt L2-resident), 3-buffer
// rotation aF[g%3] with DISTANCE-2 prefetch (~540 cyc cover vs ~200 cyc L2
// latency; round 6's distance-1 was marginal). No mid-chunk barriers; chunk
// boundary: vmcnt(8) (8 newest = two A-prefetch quads; drains the 4 B-gld16
// of chunk c+1, issued taps 0-3) + s_barrier. Never drains mid-loop.
// LDS swizzle BOTH sides (rule 21), round-4 form: phys16 = log16 ^ ((col>>1)&3)
// -> 2-way bank aliasing (free, m136). Round 6 used (col&3): 4-way conflict,
// 7.2M SQ_LDS_BANK_CONFLICT, LDS pipe became the per-tap wall. Fixed here.
__global__ __launch_bounds__(256, 2) void conv_gemm(
    const unsigned short* __restrict__ xpad,
    const unsigned short* __restrict__ Wt,
    float* __restrict__ out) {
    extern __shared__ __align__(16) char smem[];   // 32768 bytes dynamic
    const int tau = threadIdx.x;
    const int w0 = tau >> 6, l = tau & 63;
    const int lm = l & 15, lq = l >> 4;
    const int bx = blockIdx.x;
    const int tile = (bx & 7) * 112 + (bx >> 3);    // bijective XCD swizzle
    const int p0 = tile * 112;
    const int n0 = tile / 28;                       // 28 tiles per image
    const int rem0 = p0 - n0 * 3136;
    const int h0 = rem0 / 56;                       // even, 0..54

    // ---- B staging: issue i = row-slot i; thread -> col tau>>2, phys chunk
    // tau&3, fetches logical chunk (tau&3)^((col>>1)&3) ----
    const int colS = tau >> 2;
    const int logS = (tau & 3) ^ ((colS >> 1) & 3);
    const int srcB0 = (n0 * 58 + h0) * 29696 + colS * 512 + logS * 16;
    const int dstB = tau * 16;                      // + par*BBUF + slot*4096

    // ---- A direct-global: lane row = w0*64 + ti*16 + lm, k-sub lq ----
    const int laneA = (w0 * 64 + lm) * 4608 + lq * 16;   // + ti*73728 + rs*512 + c*64

    // ---- B fragment precompute: pt = tj*16+lm -> row ri, col wv ----
    int bSlot[7], wv[7];
    #pragma unroll
    for (int tj = 0; tj < 7; ++tj) {
        int pt = tj * 16 + lm;
        int ri = (pt >= 56) ? 1 : 0;
        bSlot[tj] = ri * 4096;
        wv[tj] = pt - ri * 56;
    }

    f32x4 acc[4][7] = {};
    bf16x8 aF[3][4];     // 3-buffer rotation; all indices compile-time (rule 20)

#define BAR() asm volatile("s_barrier" ::: "memory")
#define TAP(C, T) do { \
    if ((T) < 4 && (C) < 7) \
        gld16((const char*)xpad + srcB0 + (T) * 29696 + ((C) + 1) * 64, \
              smem + (((C) + 1) & 1) * BBUF + (T) * 4096 + dstB); \
    { /* distance-2 A prefetch: global tap g+2 */ \
      const int G2 = (C) * 9 + (T) + 2; \
      const int kN = (G2 % 9) * 512 + ((G2 / 9) & 7) * 64; \
      const char* ap = (const char*)Wt + laneA + kN; \
      _Pragma("unroll") \
      for (int ti = 0; ti < 4; ++ti) \
          aF[G2 % 3][ti] = *(const bf16x8*)(ap + ti * 73728); } \
    { const int r = (T) / 3, s = (T) - ((T) / 3) * 3; \
      const char* Bc = smem + ((C) & 1) * BBUF + r * 4096 + s * 64; \
      bf16x8 b[7]; \
      _Pragma("unroll") \
      for (int tj = 0; tj < 7; ++tj) { \
          const int cs = wv[tj] + s; \
          b[tj] = *(const bf16x8*)(Bc + bSlot[tj] + wv[tj] * 64 \
                    + ((lq ^ ((cs >> 1) & 3)) * 16)); } \
      __builtin_amdgcn_s_setprio(1); \
      _Pragma("unroll") \
      for (int ti = 0; ti < 4; ++ti) \
          _Pragma("unroll") \
          for (int tj = 0; tj < 7; ++tj) \
              acc[ti][tj] = __builtin_amdgcn_mfma_f32_16x16x32_bf16( \
                  aF[(((C) * 9 + (T)) % 3)][ti], b[tj], acc[ti][tj], 0, 0, 0); \
      __builtin_amdgcn_s_setprio(0); } \
    if ((T) == 8 && (C) < 7) { \
        asm volatile("s_waitcnt vmcnt(8)" ::: "memory"); \
        BAR(); \
    } \
} while (0)

    // ---- prologue: B(chunk0)->par0 (4 issues); aF for taps 0 and 1 ----
    #pragma unroll
    for (int i = 0; i < 4; ++i)
        gld16((const char*)xpad + srcB0 + i * 29696, smem + i * 4096 + dstB);
    {
        const char* ap = (const char*)Wt + laneA;
        #pragma unroll
        for (int ti = 0; ti < 4; ++ti)
            aF[0][ti] = *(const bf16x8*)(ap + ti * 73728);
        #pragma unroll
        for (int ti = 0; ti < 4; ++ti)
            aF[1][ti] = *(const bf16x8*)(ap + 512 + ti * 73728);
    }
    asm volatile("s_waitcnt vmcnt(8)" ::: "memory");   // B(c0) resident; aF rides
    BAR();

    #pragma unroll
    for (int cc = 0; cc < 4; ++cc) {
        #pragma unroll
        for (int T = 0; T < 9; ++T) TAP(2 * cc, T);
        #pragma unroll
        for (int T = 0; T < 9; ++T) TAP(2 * cc + 1, T);
    }
    asm volatile("s_waitcnt vmcnt(0)" ::: "memory");   // drain wrap prefetch

    // ---- epilogue: C/D layout col=lane&15 (spatial), row=lq*4+r2 (out-ch) ----
    const int obase0 = n0 * (K_OUT * 3136) + rem0 + lm;
    const int kb = w0 * 64 + lq * 4;
    #pragma unroll
    for (int ti = 0; ti < 4; ++ti)
        #pragma unroll
        for (int tj = 0; tj < 7; ++tj) {
            float* op = out + obase0 + tj * 16 + (kb + ti * 16) * 3136;
            #pragma unroll
            for (int r2 = 0; r2 < 4; ++r2)
                op[r2 * 3136] = acc[ti][tj][r2];
        }
#undef TAP
#undef BAR
}

// ---------------- fallback (only if ws too small): naive fp32 direct conv ----------------
__global__ void conv_naive(const float* __restrict__ x, const float* __restrict__ W,
                           float* __restrict__ out, int total) {
    int idx = blockIdx.x * 256 + threadIdx.x;
    if (idx >= total) return;
    int n = idx / (K_OUT * 3136); int rem = idx - n * (K_OUT * 3136);
    int k = rem / 3136; rem -= k * 3136;
    int h = rem / 56; int w = rem - h * 56;
    float acc = 0.f;
    for (int c = 0; c < C_IN; ++c) {
        const float* xp = x + ((n * C_IN + c) * HW) * HW;
        const float* wp = W + (k * C_IN + c) * 9;
        #pragma unroll
        for (int r = 0; r < 3; ++r) {
            int hh = h + r - 1;
            if ((unsigned)hh >= HW) continue;
            #pragma unroll
            for (int s = 0; s < 3; ++s) {
                int ww = w + s - 1;
                if ((unsigned)ww >= HW) continue;
                acc += xp[hh * HW + ww] * wp[r * 3 + s];
            }
        }
    }
    out[idx] = acc;
}

extern "C" void kernel_launch(void* const* d_in, const int* in_sizes, int n_in,
                              void* d_out, int out_size, void* d_ws, size_t ws_size,
                              hipStream_t stream) {
    const float* x = (const float*)d_in[0];
    const float* W = (const float*)d_in[1];
    float* out = (float*)d_out;
    const size_t need = (size_t)XPAD_BYTES + WT_BYTES;
    if (ws_size >= need) {
        unsigned short* xpad = (unsigned short*)d_ws;
        unsigned short* Wt = (unsigned short*)((char*)d_ws + XPAD_BYTES);
        prep<<<PREP_BLOCKS, 256, 0, stream>>>(x, W, xpad, Wt);
        conv_gemm<<<GRID_GEMM, 256, LDS_TOT, stream>>>(xpad, Wt, out);
    } else {
        conv_naive<<<(OUT_ELEMS + 255) / 256, 256, 0, stream>>>(x, W, out, OUT_ELEMS);
    }
}